// Round 1
// baseline (595.799 us; speedup 1.0000x reference)
//
#include <hip/hip_runtime.h>

#define NTHR 256

// ---------------------------------------------------------------------------
// Kernel A: one simulation step in slot order.
// Reads x from the previous step's permuted output (d_out row t-1) and isOn
// from the alternating on-buffer; computes the MLP in the exact sequential-FMA
// order a BLAS/XLA CPU microkernel uses (acc=0; fma over k in order; +bias;
// relu), produces x_new/isOn_new in slot order, and the per-block count of
// "off" rows (the stable-partition key).
// ---------------------------------------------------------------------------
__global__ __launch_bounds__(NTHR) void step_kernel(
    const float2* __restrict__ inp,
    const float* __restrict__ xsrc,
    const float* __restrict__ onsrc,
    float* __restrict__ xT,
    float* __restrict__ onT,
    unsigned* __restrict__ cnt,
    const float* __restrict__ W1, const float* __restrict__ b1,
    const float* __restrict__ W2, const float* __restrict__ b2,
    const float* __restrict__ W3, const float* __restrict__ b3,
    int t0)
{
    const int i = blockIdx.x * NTHR + threadIdx.x;
    const float2 iv = inp[i];
    const float lin  = iv.x;
    const float x    = t0 ? iv.y : xsrc[i];
    const float isOn = t0 ? 0.0f : onsrc[i];
    const bool  off  = (isOn <= 0.5f);

    // layer 1: (lin,x) @ W1(2,32) + b1, relu.  k=0 term = lin*w (fma with 0
    // addend == plain rounded mul), k=1 via fma — matches sequential-k FMA.
    float h1[32];
#pragma unroll
    for (int j = 0; j < 32; ++j) {
        float a = lin * W1[j];
        a = fmaf(x, W1[32 + j], a);
        a += b1[j];
        h1[j] = fmaxf(a, 0.0f);
    }

    // layer 2: h1 @ W2(32,32) + b2, relu; layer 3 fused (its k-order == j).
    float o = 0.0f;
#pragma unroll
    for (int j = 0; j < 32; ++j) {
        float a = 0.0f;
#pragma unroll
        for (int k = 0; k < 32; ++k)
            a = fmaf(h1[k], W2[k * 32 + j], a);   // wave-uniform -> s_load
        a += b2[j];
        a = fmaxf(a, 0.0f);
        o = fmaf(a, W3[j], o);
    }
    o += b3[0];

    const float plant = o * 10.0f;
    const float tm = x - plant;                   // both where-branches share this
    const float x_new = off ? tm : tm + 10.0f;
    const float isOn_new = off ? ((x_new <= 66.0f) ? 1.0f : isOn)
                               : ((x_new > 78.0f) ? 0.0f : isOn);
    xT[i] = x_new;
    onT[i] = isOn_new;

    // per-block count of off rows (partition key = old off flag)
    const unsigned long long m = __ballot(off);
    const int lane = threadIdx.x & 63;
    const int wv = threadIdx.x >> 6;
    __shared__ unsigned wOff[NTHR / 64];
    if (lane == 0) wOff[wv] = (unsigned)__popcll(m);
    __syncthreads();
    if (threadIdx.x == 0) {
        unsigned s = 0;
#pragma unroll
        for (int w = 0; w < NTHR / 64; ++w) s += wOff[w];
        cnt[blockIdx.x] = s;
    }
}

// ---------------------------------------------------------------------------
// Kernel B: stable partition scatter.
// Recomputes the off flag, builds the exclusive global rank of each off row
// (block-count prefix over the 1024-entry cnt array + wave ballot prefix),
// and scatters x_new/isOn_new into destination order:
//   off  row with off-rank r    -> position r
//   on   row i                  -> position N_off + (i - offBefore_i)
// xdst is d_out row t — it is simultaneously the traj output and the x state
// consumed by the next step_kernel.
// ---------------------------------------------------------------------------
__global__ __launch_bounds__(NTHR) void scatter_kernel(
    const float* __restrict__ onsrc, int t0,
    const unsigned* __restrict__ cnt,
    const float* __restrict__ xT,
    const float* __restrict__ onT,
    float* __restrict__ xdst,
    float* __restrict__ ondst)
{
    const int i = blockIdx.x * NTHR + threadIdx.x;
    const bool off = t0 ? true : (onsrc[i] <= 0.5f);

    const unsigned long long m = __ballot(off);
    const int lane = threadIdx.x & 63;
    const int wv = threadIdx.x >> 6;
    const unsigned rank = (unsigned)__popcll(m & ((1ull << lane) - 1ull));

    // block-count prefix: each thread strides over the cnt array (1024 u32,
    // L2-hot), accumulating (blocks before ours) and (total).
    unsigned before = 0, total = 0;
    const int nb = (int)gridDim.x;
    for (int b = threadIdx.x; b < nb; b += NTHR) {
        const unsigned c = cnt[b];
        total += c;
        if (b < (int)blockIdx.x) before += c;
    }
#pragma unroll
    for (int sh = 32; sh; sh >>= 1) {
        before += __shfl_down(before, sh);
        total  += __shfl_down(total, sh);
    }
    __shared__ unsigned rb[NTHR / 64], rt[NTHR / 64], wOff[NTHR / 64];
    if (lane == 0) { rb[wv] = before; rt[wv] = total; wOff[wv] = (unsigned)__popcll(m); }
    __syncthreads();
    unsigned blkBefore = 0, allTotal = 0, wExcl = 0;
#pragma unroll
    for (int w = 0; w < NTHR / 64; ++w) {
        blkBefore += rb[w];
        allTotal  += rt[w];
        if (w < wv) wExcl += wOff[w];
    }

    const unsigned offBefore = blkBefore + wExcl + rank;
    const unsigned dest = off ? offBefore : (allTotal + (unsigned)i - offBefore);
    xdst[dest]  = xT[i];
    ondst[dest] = onT[i];
}

// ---------------------------------------------------------------------------
extern "C" void kernel_launch(void* const* d_in, const int* in_sizes, int n_in,
                              void* d_out, int out_size, void* d_ws, size_t ws_size,
                              hipStream_t stream)
{
    const float2* inp = (const float2*)d_in[0];
    const float* W1 = (const float*)d_in[1];
    const float* b1 = (const float*)d_in[2];
    const float* W2 = (const float*)d_in[3];
    const float* b2 = (const float*)d_in[4];
    const float* W3 = (const float*)d_in[5];
    const float* b3 = (const float*)d_in[6];
    float* out = (float*)d_out;

    const int B = in_sizes[0] / 2;          // 262144
    const int nblk = B / NTHR;              // 1024
    const int NSTEPS = out_size / B;        // 40

    float* onA = (float*)d_ws;
    float* onB = onA + B;
    float* xT  = onB + B;
    float* onT = xT + B;
    unsigned* cnt = (unsigned*)(onT + B);

    const float* xsrc = nullptr;
    const float* onsrc = nullptr;
    for (int t = 0; t < NSTEPS; ++t) {
        const int t0 = (t == 0);
        step_kernel<<<nblk, NTHR, 0, stream>>>(inp, xsrc, onsrc, xT, onT, cnt,
                                               W1, b1, W2, b2, W3, b3, t0);
        float* xdst = out + (size_t)t * B;   // traj row t == next x state
        float* ondst = (t & 1) ? onA : onB;
        scatter_kernel<<<nblk, NTHR, 0, stream>>>(onsrc, t0, cnt, xT, onT,
                                                  xdst, ondst);
        xsrc = xdst;
        onsrc = ondst;
    }
}

// Round 2
// 522.026 us; speedup vs baseline: 1.1413x; 1.1413x over previous
//
#include <hip/hip_runtime.h>

#define NTHR 256
#define NBLK 1024   // B / NTHR

typedef unsigned long long u64;

// index of the (n+1)-th set bit of m (n is 0-based), via 6-step binary search
__device__ __forceinline__ int nth_set_bit(u64 m, unsigned n) {
    int pos = 0;
#pragma unroll
    for (int st = 32; st; st >>= 1) {
        u64 low = (1ull << (pos + st)) - 1ull;          // pos+st <= 63 always
        if ((unsigned)__popcll(m & low) <= n) pos += st;
    }
    return pos;
}

// One kernel per simulation step.
//   mode 0: first step  — x from input, isOn=0, no pull, no outRow write
//   mode 1: middle step — pull permuted state from prev step, write outRow
//                         (= traj row t-1), then compute step t
//   mode 2: final pull  — pull only, write traj row 39, no compute
// Pull: prev kernel published per-block off-counts (cntPrev) and per-wave
// 64-bit off masks (mskPrev). Each block scans cntPrev (1024 u32) into an
// LDS exclusive prefix, binary-searches the source block for its dest slot,
// then selects the wave + bit within the 64-bit mask.
__global__ __launch_bounds__(NTHR) void fused_kernel(
    const float2* __restrict__ inp,
    const float* __restrict__ W1, const float* __restrict__ b1,
    const float* __restrict__ W2, const float* __restrict__ b2,
    const float* __restrict__ W3, const float* __restrict__ b3,
    const float2* __restrict__ stPrev, const unsigned* __restrict__ cntPrev,
    const u64* __restrict__ mskPrev,
    float2* __restrict__ stNew, unsigned* __restrict__ cntNew,
    u64* __restrict__ mskNew,
    float* __restrict__ outRow,
    int mode)
{
    const int tid  = threadIdx.x;
    const int lane = tid & 63;
    const int wv   = tid >> 6;
    const int i    = blockIdx.x * NTHR + tid;

    float x, isOn;
    if (mode == 0) {
        const float2 iv = inp[i];
        x = iv.y; isOn = 0.0f;
    } else {
        // ---- exclusive block-prefix of cntPrev into LDS (4 counts/thread) ----
        __shared__ unsigned bp[NBLK];
        __shared__ unsigned wsum[NTHR / 64];
        const uint4 cc = ((const uint4*)cntPrev)[tid];
        const unsigned s = cc.x + cc.y + cc.z + cc.w;
        unsigned inc = s;
#pragma unroll
        for (int d = 1; d < 64; d <<= 1) {
            unsigned v = __shfl_up(inc, d);
            if (lane >= d) inc += v;
        }
        if (lane == 63) wsum[wv] = inc;
        __syncthreads();
        unsigned T = 0, wexcl = 0;
#pragma unroll
        for (int w = 0; w < NTHR / 64; ++w) {
            T += wsum[w];
            if (w < wv) wexcl += wsum[w];
        }
        unsigned r0 = wexcl + inc - s;          // exclusive prefix for this thread
        const unsigned base = tid * 4;
        bp[base]     = r0; r0 += cc.x;
        bp[base + 1] = r0; r0 += cc.y;
        bp[base + 2] = r0; r0 += cc.z;
        bp[base + 3] = r0;
        __syncthreads();

        // ---- source slot for destination i ----
        int src;
        if ((unsigned)i < T) {
            // i-th off row (stable order)
            const unsigned r = (unsigned)i;
            int b = 0;
#pragma unroll
            for (int st = NBLK / 2; st; st >>= 1) {
                const int nb = b + st;
                if (nb < NBLK && bp[nb] <= r) b = nb;
            }
            unsigned rr = r - bp[b];
            const u64 m0 = mskPrev[4 * b],     m1 = mskPrev[4 * b + 1];
            const u64 m2 = mskPrev[4 * b + 2], m3 = mskPrev[4 * b + 3];
            const unsigned p0 = __popcll(m0), p1 = __popcll(m1), p2 = __popcll(m2);
            int w; u64 m; unsigned nn;
            if (rr < p0)                { w = 0; m = m0; nn = rr; }
            else if (rr < p0 + p1)      { w = 1; m = m1; nn = rr - p0; }
            else if (rr < p0 + p1 + p2) { w = 2; m = m2; nn = rr - p0 - p1; }
            else                        { w = 3; m = m3; nn = rr - p0 - p1 - p2; }
            src = b * NTHR + w * 64 + nth_set_bit(m, nn);
        } else {
            // (i-T)-th on row (stable order)
            const unsigned q = (unsigned)i - T;
            int b = 0;
#pragma unroll
            for (int st = NBLK / 2; st; st >>= 1) {
                const int nb = b + st;
                if (nb < NBLK && ((unsigned)NTHR * (unsigned)nb - bp[nb]) <= q) b = nb;
            }
            unsigned qq = q - ((unsigned)NTHR * (unsigned)b - bp[b]);
            const u64 m0 = ~mskPrev[4 * b],     m1 = ~mskPrev[4 * b + 1];
            const u64 m2 = ~mskPrev[4 * b + 2], m3 = ~mskPrev[4 * b + 3];
            const unsigned p0 = __popcll(m0), p1 = __popcll(m1), p2 = __popcll(m2);
            int w; u64 m; unsigned nn;
            if (qq < p0)                { w = 0; m = m0; nn = qq; }
            else if (qq < p0 + p1)      { w = 1; m = m1; nn = qq - p0; }
            else if (qq < p0 + p1 + p2) { w = 2; m = m2; nn = qq - p0 - p1; }
            else                        { w = 3; m = m3; nn = qq - p0 - p1 - p2; }
            src = b * NTHR + w * 64 + nth_set_bit(m, nn);
        }
        const float2 sv = stPrev[src];
        x = sv.x; isOn = sv.y;
        outRow[i] = x;                 // traj row t-1 (permuted x_new of t-1)
        if (mode == 2) return;
    }

    const float lin = inp[i].x;
    const bool  off = (isOn <= 0.5f);  // partition key & update branch (pre-update)

    // ---- MLP, byte-identical arithmetic order to the validated round-1 kernel ----
    float h1[32];
#pragma unroll
    for (int j = 0; j < 32; ++j) {
        float a = lin * W1[j];
        a = fmaf(x, W1[32 + j], a);
        a += b1[j];
        h1[j] = fmaxf(a, 0.0f);
    }
    float o = 0.0f;
#pragma unroll
    for (int j = 0; j < 32; ++j) {
        float a = 0.0f;
#pragma unroll
        for (int k = 0; k < 32; ++k)
            a = fmaf(h1[k], W2[k * 32 + j], a);   // wave-uniform weights -> s_load
        a += b2[j];
        a = fmaxf(a, 0.0f);
        o = fmaf(a, W3[j], o);
    }
    o += b3[0];

    const float plant = o * 10.0f;
    const float tm = x - plant;
    const float x_new = off ? tm : tm + 10.0f;
    const float isOn_new = off ? ((x_new <= 66.0f) ? 1.0f : isOn)
                               : ((x_new > 78.0f) ? 0.0f : isOn);

    stNew[i] = make_float2(x_new, isOn_new);

    // ---- publish partition info for the next kernel's pull ----
    const u64 m = __ballot(off);
    __shared__ unsigned wOff[NTHR / 64];
    if (lane == 0) { mskNew[i >> 6] = m; wOff[wv] = (unsigned)__popcll(m); }
    __syncthreads();
    if (tid == 0) {
        unsigned ssum = 0;
#pragma unroll
        for (int w = 0; w < NTHR / 64; ++w) ssum += wOff[w];
        cntNew[blockIdx.x] = ssum;
    }
}

// ---------------------------------------------------------------------------
extern "C" void kernel_launch(void* const* d_in, const int* in_sizes, int n_in,
                              void* d_out, int out_size, void* d_ws, size_t ws_size,
                              hipStream_t stream)
{
    const float2* inp = (const float2*)d_in[0];
    const float* W1 = (const float*)d_in[1];
    const float* b1 = (const float*)d_in[2];
    const float* W2 = (const float*)d_in[3];
    const float* b2 = (const float*)d_in[4];
    const float* W3 = (const float*)d_in[5];
    const float* b3 = (const float*)d_in[6];
    float* out = (float*)d_out;

    const int B = in_sizes[0] / 2;          // 262144
    const int NSTEPS = out_size / B;        // 40

    float2*   stA  = (float2*)d_ws;
    float2*   stB  = stA + B;
    unsigned* cntA = (unsigned*)(stB + B);
    unsigned* cntB = cntA + NBLK;
    u64*      mskA = (u64*)(cntB + NBLK);
    u64*      mskB = mskA + (B / 64);

    // step 0: no pull
    fused_kernel<<<NBLK, NTHR, 0, stream>>>(inp, W1, b1, W2, b2, W3, b3,
                                            stA, cntA, mskA,
                                            stA, cntA, mskA,
                                            nullptr, 0);
    // steps 1..NSTEPS-1: pull prev (writes traj row t-1) + compute step t
    for (int t = 1; t < NSTEPS; ++t) {
        const bool odd = (t & 1);
        const float2*   stP  = odd ? stA  : stB;
        const unsigned* cntP = odd ? cntA : cntB;
        const u64*      mskP = odd ? mskA : mskB;
        float2*   stN  = odd ? stB  : stA;
        unsigned* cntN = odd ? cntB : cntA;
        u64*      mskN = odd ? mskB : mskA;
        fused_kernel<<<NBLK, NTHR, 0, stream>>>(inp, W1, b1, W2, b2, W3, b3,
                                                stP, cntP, mskP,
                                                stN, cntN, mskN,
                                                out + (size_t)(t - 1) * B, 1);
    }
    // final pull-only: traj row NSTEPS-1
    {
        const bool odd = (NSTEPS & 1);      // parity of the "virtual" step NSTEPS
        const float2*   stP  = odd ? stA  : stB;
        const unsigned* cntP = odd ? cntA : cntB;
        const u64*      mskP = odd ? mskA : mskB;
        fused_kernel<<<NBLK, NTHR, 0, stream>>>(inp, W1, b1, W2, b2, W3, b3,
                                                stP, cntP, mskP,
                                                stA, cntA, mskA,   // unused
                                                out + (size_t)(NSTEPS - 1) * B, 2);
    }
}